// Round 1
// baseline (853.893 us; speedup 1.0000x reference)
//
#include <hip/hip_runtime.h>
#include <cstdint>

// Problem constants (static per reference)
#define EMBED 256
#define HEADS 8
#define HD 32
#define LEVELS 4
#define POINTS 4
#define BS 2
#define NQ 16384
#define NV 21760   // 128*128 + 64*64 + 32*32 + 16*16

// ---------------------------------------------------------------------------
// Generic fp32 GEMM: C(MxN) = A(Mx256) @ W(256xN) + bias (+res) (relu?)
// A row remap: rows_inner==0 -> dense row r; else row r -> b*inner+n maps to
// A[(n*BS + b)*256] (handles (seq, bs, C)-layout inputs), optional A2 added.
// BM=BN=64, BK=16, 256 threads, 4x4 per thread.
// ---------------------------------------------------------------------------
#define BM 64
#define BN 64
#define BK 16

__global__ __launch_bounds__(256) void gemm_f32(
    const float* __restrict__ A, const float* __restrict__ A2,
    const float* __restrict__ W, const float* __restrict__ bias,
    const float* __restrict__ res, float* __restrict__ C,
    int M, int N, int rows_inner, int relu)
{
    __shared__ float As[BK][BM + 4];   // +4 pad: keeps 16B alignment, kills store conflicts
    __shared__ float Bs[BK][BN];

    const int t  = threadIdx.x;
    const int bm = blockIdx.y, bn = blockIdx.x;

    // A tile load mapping: 64 rows x 16 k  (one float4 per thread)
    const int arow = t >> 2;
    const int akc  = (t & 3) * 4;
    // B tile load mapping: 16 k-rows x 64 cols (one float4 per thread)
    const int bkrow = t >> 4;
    const int bnc   = (t & 15) * 4;

    const int row = bm * BM + arow;
    int aoff;
    if (rows_inner) {
        const int b = row / rows_inner;
        const int n = row - b * rows_inner;
        aoff = (n * BS + b) * EMBED;
    } else {
        aoff = row * EMBED;
    }

    const int ty = t >> 4, tx = t & 15;
    float acc[4][4];
#pragma unroll
    for (int i = 0; i < 4; ++i)
#pragma unroll
        for (int j = 0; j < 4; ++j) acc[i][j] = 0.f;

    for (int k0 = 0; k0 < EMBED; k0 += BK) {
        float4 a4 = *reinterpret_cast<const float4*>(A + aoff + k0 + akc);
        if (A2) {
            float4 b4 = *reinterpret_cast<const float4*>(A2 + aoff + k0 + akc);
            a4.x += b4.x; a4.y += b4.y; a4.z += b4.z; a4.w += b4.w;
        }
        As[akc + 0][arow] = a4.x;
        As[akc + 1][arow] = a4.y;
        As[akc + 2][arow] = a4.z;
        As[akc + 3][arow] = a4.w;

        float4 w4 = *reinterpret_cast<const float4*>(W + (size_t)(k0 + bkrow) * N + bn * BN + bnc);
        *reinterpret_cast<float4*>(&Bs[bkrow][bnc]) = w4;

        __syncthreads();
#pragma unroll
        for (int k = 0; k < BK; ++k) {
            float4 av = *reinterpret_cast<float4*>(&As[k][ty * 4]);
            float4 bv = *reinterpret_cast<float4*>(&Bs[k][tx * 4]);
            acc[0][0] += av.x * bv.x; acc[0][1] += av.x * bv.y; acc[0][2] += av.x * bv.z; acc[0][3] += av.x * bv.w;
            acc[1][0] += av.y * bv.x; acc[1][1] += av.y * bv.y; acc[1][2] += av.y * bv.z; acc[1][3] += av.y * bv.w;
            acc[2][0] += av.z * bv.x; acc[2][1] += av.z * bv.y; acc[2][2] += av.z * bv.z; acc[2][3] += av.z * bv.w;
            acc[3][0] += av.w * bv.x; acc[3][1] += av.w * bv.y; acc[3][2] += av.w * bv.z; acc[3][3] += av.w * bv.w;
        }
        __syncthreads();
    }

#pragma unroll
    for (int i = 0; i < 4; ++i) {
        const int r = bm * BM + ty * 4 + i;
#pragma unroll
        for (int j = 0; j < 4; ++j) {
            const int c = bn * BN + tx * 4 + j;
            float v = acc[i][j];
            if (bias) v += bias[c];
            if (res)  v += res[(size_t)r * N + c];
            if (relu) v = fmaxf(v, 0.f);
            C[(size_t)r * N + c] = v;
        }
    }
}

// ---------------------------------------------------------------------------
// Deformable-attention sampler. One block per (b, q) pair (rb = b*NQ + q).
// Thread t: head h = t>>5, dim d = t&31. Softmax over 16 (l,p) per head
// computed in-block from raw attn logits. Writes out row (q*BS + b) (nq-major)
// so the out-projection GEMM is a plain dense GEMM with lidar_feat residual.
// ---------------------------------------------------------------------------
__global__ __launch_bounds__(256) void sampler_k(
    const float* __restrict__ off, const float* __restrict__ aw_raw,
    const float* __restrict__ ref2d, const float* __restrict__ v,
    float* __restrict__ out)
{
    const int rb = blockIdx.x;          // b*NQ + q
    const int b  = rb >> 14;            // NQ = 16384
    const int qi = rb & (NQ - 1);
    const int t  = threadIdx.x;

    __shared__ float s_off[256];
    __shared__ float s_aw[128];
    __shared__ float s_ref[8];

    s_off[t] = off[(size_t)rb * 256 + t];
    if (t < 128) s_aw[t] = aw_raw[(size_t)rb * 128 + t];
    if (t < 8)   s_ref[t] = ref2d[(size_t)rb * 8 + t];
    __syncthreads();

    if (t < 8) {   // per-head softmax over 16 logits
        float m = -1e30f;
#pragma unroll
        for (int i = 0; i < 16; ++i) m = fmaxf(m, s_aw[t * 16 + i]);
        float e[16], s = 0.f;
#pragma unroll
        for (int i = 0; i < 16; ++i) { e[i] = expf(s_aw[t * 16 + i] - m); s += e[i]; }
        const float inv = 1.f / s;
#pragma unroll
        for (int i = 0; i < 16; ++i) s_aw[t * 16 + i] = e[i] * inv;
    }
    __syncthreads();

    const int h = t >> 5, d = t & 31;
    const int Wl[LEVELS] = {128, 64, 32, 16};
    const int S0[LEVELS] = {0, 16384, 20480, 21504};

    float acc = 0.f;
    const float* vb = v + (size_t)b * NV * EMBED;

#pragma unroll
    for (int l = 0; l < LEVELS; ++l) {
        const int   Wi = Wl[l];             // square levels: H == W
        const float Wf = (float)Wi;
        const float refx = s_ref[l * 2 + 0];
        const float refy = s_ref[l * 2 + 1];
        const int base = S0[l];
#pragma unroll
        for (int p = 0; p < POINTS; ++p) {
            const int oi = ((h * LEVELS + l) * POINTS + p) * 2;
            const float locx = refx + s_off[oi + 0] / Wf;
            const float locy = refy + s_off[oi + 1] / Wf;
            const float x = locx * Wf - 0.5f;
            const float y = locy * Wf - 0.5f;
            const float x0f = floorf(x), y0f = floorf(y);
            const float lx = x - x0f, ly = y - y0f;
            const int x0 = (int)x0f, y0 = (int)y0f;

            const float a = s_aw[h * 16 + l * POINTS + p];
            const float w00 = (1.f - lx) * (1.f - ly) * a;
            const float w10 = lx * (1.f - ly) * a;
            const float w01 = (1.f - lx) * ly * a;
            const float w11 = lx * ly * a;

            const bool vx0 = (x0 >= 0)     && (x0 < Wi);
            const bool vx1 = (x0 + 1 >= 0) && (x0 + 1 < Wi);
            const bool vy0 = (y0 >= 0)     && (y0 < Wi);
            const bool vy1 = (y0 + 1 >= 0) && (y0 + 1 < Wi);

            if (vx0 && vy0) acc += w00 * vb[((size_t)(base + y0 * Wi + x0)       * HEADS + h) * HD + d];
            if (vx1 && vy0) acc += w10 * vb[((size_t)(base + y0 * Wi + x0 + 1)   * HEADS + h) * HD + d];
            if (vx0 && vy1) acc += w01 * vb[((size_t)(base + (y0+1) * Wi + x0)   * HEADS + h) * HD + d];
            if (vx1 && vy1) acc += w11 * vb[((size_t)(base + (y0+1) * Wi + x0+1) * HEADS + h) * HD + d];
        }
    }
    // write nq-major: row = qi*BS + b, col = h*32 + d == t
    out[((size_t)(qi * BS + b)) * 256 + t] = acc;
}

// ---------------------------------------------------------------------------
// LayerNorm over rows of 256. One block (256 threads) per row. In-place safe.
// ---------------------------------------------------------------------------
__global__ __launch_bounds__(256) void ln_k(
    const float* __restrict__ xin, const float* __restrict__ g,
    const float* __restrict__ bb, float* __restrict__ xout)
{
    const int r = blockIdx.x, t = threadIdx.x;
    float v = xin[(size_t)r * 256 + t];

    __shared__ float red[4];
    float s = v;
#pragma unroll
    for (int o = 32; o > 0; o >>= 1) s += __shfl_xor(s, o);
    if ((t & 63) == 0) red[t >> 6] = s;
    __syncthreads();
    const float mu = (red[0] + red[1] + red[2] + red[3]) * (1.f / 256.f);
    __syncthreads();

    const float d = v - mu;
    float ss = d * d;
#pragma unroll
    for (int o = 32; o > 0; o >>= 1) ss += __shfl_xor(ss, o);
    if ((t & 63) == 0) red[t >> 6] = ss;
    __syncthreads();
    const float var = (red[0] + red[1] + red[2] + red[3]) * (1.f / 256.f);

    xout[(size_t)r * 256 + t] = d * rsqrtf(var + 1e-5f) * g[t] + bb[t];
}

// ---------------------------------------------------------------------------
extern "C" void kernel_launch(void* const* d_in, const int* in_sizes, int n_in,
                              void* d_out, int out_size, void* d_ws, size_t ws_size,
                              hipStream_t stream)
{
    const float* lidar  = (const float*)d_in[0];   // (NQ, BS, 256)
    const float* feat   = (const float*)d_in[1];   // (NV, BS, 256)
    const float* ref2d  = (const float*)d_in[2];   // (BS, NQ, 4, 2)
    const float* q_pose = (const float*)d_in[5];   // (NQ, BS, 256)
    const float* W_off  = (const float*)d_in[6];
    const float* b_off  = (const float*)d_in[7];
    const float* W_attn = (const float*)d_in[8];
    const float* b_attn = (const float*)d_in[9];
    const float* W_val  = (const float*)d_in[10];
    const float* b_val  = (const float*)d_in[11];
    const float* W_out  = (const float*)d_in[12];
    const float* b_out  = (const float*)d_in[13];
    const float* ln1_g  = (const float*)d_in[14];
    const float* ln1_b  = (const float*)d_in[15];
    const float* ffn_w1 = (const float*)d_in[16];
    const float* ffn_w2 = (const float*)d_in[17];
    const float* ln2_g  = (const float*)d_in[18];
    const float* ln2_b  = (const float*)d_in[19];

    float* out = (float*)d_out;                    // (NQ, BS, 256)
    float* ws  = (float*)d_ws;

    // Workspace layout (floats). Total 32,112,640 floats = 128.5 MB.
    const size_t OFF_V   = 0;                       // v:   43520*256 = 11,141,120
    const size_t OFF_OFF = 11141120;                // off: 32768*256 =  8,388,608
    const size_t OFF_AW  = 19529728;                // aw:  32768*128 =  4,194,304
    const size_t OFF_SMP = 23724032;                // smp: 32768*256 =  8,388,608
    float* v_buf   = ws + OFF_V;
    float* off_buf = ws + OFF_OFF;
    float* aw_buf  = ws + OFF_AW;
    float* smp     = ws + OFF_SMP;
    float* xbuf    = ws + OFF_V;                    // reuse v (dead after sampler)
    float* h1      = ws + OFF_OFF;                  // reuse off/aw (dead after sampler)

    const int MQ = BS * NQ;    // 32768
    const int MV = BS * NV;    // 43520
    dim3 blk(256);

    // 1. value projection: v = featT @ W_val + b_val   (rows b*NV+n, interleaved A)
    gemm_f32<<<dim3(256 / BN, MV / BM), blk, 0, stream>>>(
        feat, nullptr, W_val, b_val, nullptr, v_buf, MV, 256, NV, 0);

    // 2. offsets: (lidar+q_pose) @ W_off + b_off  (rows b*NQ+q)
    gemm_f32<<<dim3(256 / BN, MQ / BM), blk, 0, stream>>>(
        lidar, q_pose, W_off, b_off, nullptr, off_buf, MQ, 256, NQ, 0);

    // 3. attn logits: (lidar+q_pose) @ W_attn + b_attn
    gemm_f32<<<dim3(128 / BN, MQ / BM), blk, 0, stream>>>(
        lidar, q_pose, W_attn, b_attn, nullptr, aw_buf, MQ, 128, NQ, 0);

    // 4. deformable sampling (+softmax) -> smp (nq-major rows)
    sampler_k<<<dim3(MQ), blk, 0, stream>>>(off_buf, aw_buf, ref2d, v_buf, smp);

    // 5. out-projection + bias + identity residual -> xbuf
    gemm_f32<<<dim3(256 / BN, MQ / BM), blk, 0, stream>>>(
        smp, nullptr, W_out, b_out, lidar, xbuf, MQ, 256, 0, 0);

    // 6. LN1 (in-place)
    ln_k<<<dim3(MQ), blk, 0, stream>>>(xbuf, ln1_g, ln1_b, xbuf);

    // 7. FFN1: relu(x @ ffn_w1)
    gemm_f32<<<dim3(256 / BN, MQ / BM), blk, 0, stream>>>(
        xbuf, nullptr, ffn_w1, nullptr, nullptr, h1, MQ, 256, 0, 1);

    // 8. FFN2: h1 @ ffn_w2 + x -> d_out
    gemm_f32<<<dim3(256 / BN, MQ / BM), blk, 0, stream>>>(
        h1, nullptr, ffn_w2, nullptr, xbuf, out, MQ, 256, 0, 0);

    // 9. LN2 (in-place on d_out)
    ln_k<<<dim3(MQ), blk, 0, stream>>>(out, ln2_g, ln2_b, out);
}

// Round 2
// 304.417 us; speedup vs baseline: 2.8050x; 2.8050x over previous
//
#include <hip/hip_runtime.h>
#include <cstdint>

#define EMBED 256
#define HEADS 8
#define HD 32
#define LEVELS 4
#define POINTS 4
#define BS 2
#define NQ 16384
#define NV 21760          // 128*128+64*64+32*32+16*16
#define MQ (BS*NQ)        // 32768
#define MV (BS*NV)        // 43520

typedef __attribute__((ext_vector_type(8))) short short8;
typedef __attribute__((ext_vector_type(4))) float f32x4;

__device__ __forceinline__ unsigned short f2bf(float f) {
    unsigned int u = __float_as_uint(f);
    u = (u + 0x7FFFu + ((u >> 16) & 1u)) >> 16;   // RNE
    return (unsigned short)u;
}
__device__ __forceinline__ float bf2f(unsigned short h) {
    return __uint_as_float(((unsigned int)h) << 16);
}

// ---------------------------------------------------------------------------
// prep_rows: dst[b*inner+n][c] = bf16(s1[(n*BS+b)*256+c] (+ s2[...]))
// grid = M/4 blocks, 256 threads; 4 rows/block, float4 per thread.
// ---------------------------------------------------------------------------
__global__ __launch_bounds__(256) void prep_rows(
    const float* __restrict__ s1, const float* __restrict__ s2,
    unsigned short* __restrict__ dst, int inner)
{
    const int t = threadIdx.x;
    const int r = blockIdx.x * 4 + (t >> 6);
    const int c = (t & 63) * 4;
    const int b = r / inner, n = r - b * inner;
    const size_t src = (size_t)(n * BS + b) * 256 + c;
    float4 v = *reinterpret_cast<const float4*>(s1 + src);
    if (s2) {
        float4 w = *reinterpret_cast<const float4*>(s2 + src);
        v.x += w.x; v.y += w.y; v.z += w.z; v.w += w.w;
    }
    ushort4 o; o.x = f2bf(v.x); o.y = f2bf(v.y); o.z = f2bf(v.z); o.w = f2bf(v.w);
    *reinterpret_cast<ushort4*>(dst + (size_t)r * 256 + c) = o;
}

// ---------------------------------------------------------------------------
// prep_wt: Wt[n][k] = bf16(W[k][n]) for 6 weight matrices. grid (256, 6).
// ---------------------------------------------------------------------------
struct WtArgs {
    const float* src[6];
    unsigned short* dst[6];
    int n[6];
};
__global__ __launch_bounds__(256) void prep_wt(WtArgs a)
{
    const int g = blockIdx.y;
    const int N = a.n[g];
    const int e = blockIdx.x * 256 + threadIdx.x;
    if (e >= 256 * N) return;
    const int k = e / N, n = e - k * N;
    a.dst[g][(size_t)n * 256 + k] = f2bf(a.src[g][e]);
}

// ---------------------------------------------------------------------------
// bf16 MFMA GEMM: out(M x N) = A(M x 256) @ Wt^T + bias (+res) (relu?)
// A bf16 row-major [M][256]; Wt bf16 [N][256] (k-major rows).
// 128x128 tile, BK=32, 4 waves, each wave 4x4 frags of 16x16x32.
// global_load_lds(16B) staging, k-slot XOR swizzle via pre-swizzled source.
// ---------------------------------------------------------------------------
__global__ __launch_bounds__(256) void gemm_mfma(
    const unsigned short* __restrict__ A, const unsigned short* __restrict__ Bt,
    const float* __restrict__ bias, const float* __restrict__ res,
    float* __restrict__ outf, unsigned short* __restrict__ outh,
    int N, int relu)
{
    __shared__ unsigned short As[128 * 32];
    __shared__ unsigned short Bs[128 * 32];
    const int t = threadIdx.x, l = t & 63, w = t >> 6;
    const size_t brow = (size_t)blockIdx.y * 128;
    const int bcol = blockIdx.x * 128;
    const int wm = w & 1, wn = w >> 1;

    // staging: lane l covers row (seg*16 + (l>>2)), k-slot (l&3), 16B each.
    const int srow = l >> 2;
    const int sslot = (l & 3) ^ ((srow & 3) ^ ((srow >> 2) & 3));  // pre-swizzled src slot
    // fragment read: lane l reads row (l&15), global k-slot (l>>4) -> swizzled lds slot
    const int frow = l & 15;
    const int fslot = (l >> 4) ^ ((frow & 3) ^ ((frow >> 2) & 3));

    f32x4 acc[4][4];
#pragma unroll
    for (int i = 0; i < 4; ++i)
#pragma unroll
        for (int j = 0; j < 4; ++j) acc[i][j] = f32x4{0.f, 0.f, 0.f, 0.f};

    const unsigned short* ga0 = A + (brow + (size_t)(w * 16 + srow)) * 256 + sslot * 8;
    const unsigned short* ga1 = ga0 + (size_t)64 * 256;
    const unsigned short* gb0 = Bt + ((size_t)bcol + (size_t)(w * 16 + srow)) * 256 + sslot * 8;
    const unsigned short* gb1 = gb0 + (size_t)64 * 256;

    for (int k0 = 0; k0 < 256; k0 += 32) {
        __builtin_amdgcn_global_load_lds(
            (const __attribute__((address_space(1))) void*)(ga0 + k0),
            (__attribute__((address_space(3))) void*)&As[w * 512], 16, 0, 0);
        __builtin_amdgcn_global_load_lds(
            (const __attribute__((address_space(1))) void*)(ga1 + k0),
            (__attribute__((address_space(3))) void*)&As[(w + 4) * 512], 16, 0, 0);
        __builtin_amdgcn_global_load_lds(
            (const __attribute__((address_space(1))) void*)(gb0 + k0),
            (__attribute__((address_space(3))) void*)&Bs[w * 512], 16, 0, 0);
        __builtin_amdgcn_global_load_lds(
            (const __attribute__((address_space(1))) void*)(gb1 + k0),
            (__attribute__((address_space(3))) void*)&Bs[(w + 4) * 512], 16, 0, 0);
        __syncthreads();

        short8 af[4], bq[4];
#pragma unroll
        for (int fm = 0; fm < 4; ++fm)
            af[fm] = *reinterpret_cast<const short8*>(&As[(wm * 64 + fm * 16 + frow) * 32 + fslot * 8]);
#pragma unroll
        for (int fn = 0; fn < 4; ++fn)
            bq[fn] = *reinterpret_cast<const short8*>(&Bs[(wn * 64 + fn * 16 + frow) * 32 + fslot * 8]);
#pragma unroll
        for (int fm = 0; fm < 4; ++fm)
#pragma unroll
            for (int fn = 0; fn < 4; ++fn)
                acc[fm][fn] = __builtin_amdgcn_mfma_f32_16x16x32_bf16(af[fm], bq[fn], acc[fm][fn], 0, 0, 0);
        __syncthreads();
    }

    // epilogue: D col = lane&15, row = (lane>>4)*4 + j   [guide m89]
#pragma unroll
    for (int fm = 0; fm < 4; ++fm) {
#pragma unroll
        for (int fn = 0; fn < 4; ++fn) {
            const int col = bcol + wn * 64 + fn * 16 + frow;
            const float bv = bias ? bias[col] : 0.f;
#pragma unroll
            for (int j = 0; j < 4; ++j) {
                const size_t row = brow + wm * 64 + fm * 16 + (l >> 4) * 4 + j;
                float v = acc[fm][fn][j] + bv;
                if (res)  v += res[row * N + col];
                if (relu) v = fmaxf(v, 0.f);
                if (outf) outf[row * N + col] = v;
                else      outh[row * N + col] = f2bf(v);
            }
        }
    }
}

// ---------------------------------------------------------------------------
// Deformable sampler, bf16 v. Descriptor phase (128 thr) computes per-(h,l,p)
// corner weights + clamped element offsets once; gather phase (256 thr) is
// branchless  acc += w * bf16(v[ofs + d]).
// ---------------------------------------------------------------------------
__global__ __launch_bounds__(256) void sampler_k(
    const unsigned short* __restrict__ off, const unsigned short* __restrict__ aw_raw,
    const float* __restrict__ ref2d, const unsigned short* __restrict__ v,
    unsigned short* __restrict__ outh)
{
    const int rb = blockIdx.x;          // b*NQ + q
    const int b = rb >> 14, qi = rb & (NQ - 1);
    const int t = threadIdx.x;

    __shared__ float s_off[256];
    __shared__ float s_aw[128];
    __shared__ float s_ref[8];
    __shared__ uint2 s_d[128 * 4];      // (.x = weight bits, .y = element offset)

    s_off[t] = bf2f(off[(size_t)rb * 256 + t]);
    if (t < 128) s_aw[t] = bf2f(aw_raw[(size_t)rb * 128 + t]);
    if (t < 8)   s_ref[t] = ref2d[(size_t)rb * 8 + t];
    __syncthreads();

    if (t < 8) {                        // per-head softmax over 16
        float m = -1e30f;
#pragma unroll
        for (int i = 0; i < 16; ++i) m = fmaxf(m, s_aw[t * 16 + i]);
        float e[16], s = 0.f;
#pragma unroll
        for (int i = 0; i < 16; ++i) { e[i] = __expf(s_aw[t * 16 + i] - m); s += e[i]; }
        const float inv = 1.f / s;
#pragma unroll
        for (int i = 0; i < 16; ++i) s_aw[t * 16 + i] = e[i] * inv;
    }
    __syncthreads();

    if (t < 128) {                      // t = h*16 + (l*4+p)
        const int h = t >> 4, lp = t & 15, li = lp >> 2;
        const int Wl[4] = {128, 64, 32, 16};
        const int S0[4] = {0, 16384, 20480, 21504};
        const int Wi = Wl[li];
        const float Wf = (float)Wi;
        const int oi = t * 2;           // (h*16+lp)*2 == ((h*4+l)*4+p)*2
        const float x = (s_ref[li * 2 + 0] + s_off[oi + 0] / Wf) * Wf - 0.5f;
        const float y = (s_ref[li * 2 + 1] + s_off[oi + 1] / Wf) * Wf - 0.5f;
        const float x0f = floorf(x), y0f = floorf(y);
        const float lx = x - x0f, ly = y - y0f;
        const int x0 = (int)x0f, y0 = (int)y0f;
        const float a = s_aw[t];
        const float cw[4] = {(1.f - lx) * (1.f - ly) * a, lx * (1.f - ly) * a,
                             (1.f - lx) * ly * a,          lx * ly * a};
        const int base = b * NV + S0[li];
#pragma unroll
        for (int c = 0; c < 4; ++c) {
            const int xi = x0 + (c & 1), yi = y0 + (c >> 1);
            const bool val = (xi >= 0) & (xi < Wi) & (yi >= 0) & (yi < Wi);
            const int xc = min(max(xi, 0), Wi - 1), yc = min(max(yi, 0), Wi - 1);
            const unsigned int ofs = (unsigned int)(base + yc * Wi + xc) * 256u + h * 32;
            s_d[t * 4 + c] = make_uint2(__float_as_uint(val ? cw[c] : 0.f), ofs);
        }
    }
    __syncthreads();

    const int h = t >> 5, d = t & 31;
    float acc = 0.f;
#pragma unroll
    for (int i = 0; i < 16; ++i) {
#pragma unroll
        for (int c = 0; c < 4; ++c) {
            const uint2 dd = s_d[(h * 16 + i) * 4 + c];
            acc += __uint_as_float(dd.x) * bf2f(v[(size_t)dd.y + d]);
        }
    }
    outh[((size_t)(qi * BS + b)) * 256 + t] = f2bf(acc);   // nq-major row
}

// ---------------------------------------------------------------------------
// LayerNorm over rows of 256; optional secondary bf16 output.
// ---------------------------------------------------------------------------
__global__ __launch_bounds__(256) void ln_k(
    const float* __restrict__ xin, const float* __restrict__ g,
    const float* __restrict__ bb, float* __restrict__ xoutf,
    unsigned short* __restrict__ xouth)
{
    const int r = blockIdx.x, t = threadIdx.x;
    const size_t idx = (size_t)r * 256 + t;
    float v = xin[idx];

    __shared__ float red[4];
    float s = v;
#pragma unroll
    for (int o = 32; o > 0; o >>= 1) s += __shfl_xor(s, o);
    if ((t & 63) == 0) red[t >> 6] = s;
    __syncthreads();
    const float mu = (red[0] + red[1] + red[2] + red[3]) * (1.f / 256.f);
    __syncthreads();

    const float dlt = v - mu;
    float ss = dlt * dlt;
#pragma unroll
    for (int o = 32; o > 0; o >>= 1) ss += __shfl_xor(ss, o);
    if ((t & 63) == 0) red[t >> 6] = ss;
    __syncthreads();
    const float var = (red[0] + red[1] + red[2] + red[3]) * (1.f / 256.f);

    const float y = dlt * rsqrtf(var + 1e-5f) * g[t] + bb[t];
    if (xoutf) xoutf[idx] = y;
    if (xouth) xouth[idx] = f2bf(y);
}

// ---------------------------------------------------------------------------
extern "C" void kernel_launch(void* const* d_in, const int* in_sizes, int n_in,
                              void* d_out, int out_size, void* d_ws, size_t ws_size,
                              hipStream_t stream)
{
    const float* lidar  = (const float*)d_in[0];
    const float* feat   = (const float*)d_in[1];
    const float* ref2d  = (const float*)d_in[2];
    const float* q_pose = (const float*)d_in[5];
    const float* W_off  = (const float*)d_in[6];
    const float* b_off  = (const float*)d_in[7];
    const float* W_attn = (const float*)d_in[8];
    const float* b_attn = (const float*)d_in[9];
    const float* W_val  = (const float*)d_in[10];
    const float* b_val  = (const float*)d_in[11];
    const float* W_out  = (const float*)d_in[12];
    const float* b_out  = (const float*)d_in[13];
    const float* ln1_g  = (const float*)d_in[14];
    const float* ln1_b  = (const float*)d_in[15];
    const float* ffn_w1 = (const float*)d_in[16];
    const float* ffn_w2 = (const float*)d_in[17];
    const float* ln2_g  = (const float*)d_in[18];
    const float* ln2_b  = (const float*)d_in[19];

    float* out = (float*)d_out;
    char*  ws  = (char*)d_ws;

    // byte offsets; high-water 104,005,632 B (< 128.5 MB used in R1)
    unsigned short* qb    = (unsigned short*)(ws + 0);          // 16.78 MB
    unsigned short* featb = (unsigned short*)(ws + 16777216);   // 22.28 MB
    unsigned short* vb    = (unsigned short*)(ws + 39059456);   // 22.28 MB
    unsigned short* offb  = (unsigned short*)(ws + 61341696);   // 16.78 MB
    unsigned short* awb   = (unsigned short*)(ws + 78118912);   //  8.39 MB
    unsigned short* smp   = (unsigned short*)(ws + 86507520);   // 16.78 MB
    float*          xbuf  = (float*)(ws + 16777216);            // 33.55 MB (aliases featb+vb, dead)
    unsigned short* xln   = (unsigned short*)(ws + 61341696);   // aliases offb (dead)
    unsigned short* h1b   = (unsigned short*)(ws + 78118912);   // aliases awb/smp-head (dead)
    unsigned short* wt    = (unsigned short*)(ws + 103284736);  // 0.72 MB
    unsigned short* wt_val = wt, *wt_off = wt + 65536, *wt_attn = wt + 131072,
                  *wt_out = wt + 163840, *wt_f1 = wt + 229376, *wt_f2 = wt + 294912;

    dim3 blk(256);

    // pre-convert inputs to bf16
    prep_rows<<<dim3(MQ / 4), blk, 0, stream>>>(lidar, q_pose, qb, NQ);
    prep_rows<<<dim3(MV / 4), blk, 0, stream>>>(feat, nullptr, featb, NV);
    WtArgs wa;
    wa.src[0] = W_val;  wa.dst[0] = wt_val;  wa.n[0] = 256;
    wa.src[1] = W_off;  wa.dst[1] = wt_off;  wa.n[1] = 256;
    wa.src[2] = W_attn; wa.dst[2] = wt_attn; wa.n[2] = 128;
    wa.src[3] = W_out;  wa.dst[3] = wt_out;  wa.n[3] = 256;
    wa.src[4] = ffn_w1; wa.dst[4] = wt_f1;   wa.n[4] = 256;
    wa.src[5] = ffn_w2; wa.dst[5] = wt_f2;   wa.n[5] = 256;
    prep_wt<<<dim3(256, 6), blk, 0, stream>>>(wa);

    // projections (MFMA)
    gemm_mfma<<<dim3(2, MV / 128), blk, 0, stream>>>(featb, wt_val, b_val, nullptr, nullptr, vb, 256, 0);
    gemm_mfma<<<dim3(2, MQ / 128), blk, 0, stream>>>(qb, wt_off, b_off, nullptr, nullptr, offb, 256, 0);
    gemm_mfma<<<dim3(1, MQ / 128), blk, 0, stream>>>(qb, wt_attn, b_attn, nullptr, nullptr, awb, 128, 0);

    // deformable sampling (+softmax), writes bf16 nq-major
    sampler_k<<<dim3(MQ), blk, 0, stream>>>(offb, awb, ref2d, vb, smp);

    // out-projection + bias + residual (lidar is dense in nq-major) -> f32
    gemm_mfma<<<dim3(2, MQ / 128), blk, 0, stream>>>(smp, wt_out, b_out, lidar, xbuf, nullptr, 256, 0);

    // LN1 (f32 in-place + bf16 copy for FFN1 A)
    ln_k<<<dim3(MQ), blk, 0, stream>>>(xbuf, ln1_g, ln1_b, xbuf, xln);

    // FFN1: relu(x @ w1) -> bf16 (no bias in reference)
    gemm_mfma<<<dim3(2, MQ / 128), blk, 0, stream>>>(xln, wt_f1, nullptr, nullptr, nullptr, h1b, 256, 1);

    // FFN2: h1 @ w2 + x -> d_out (f32)
    gemm_mfma<<<dim3(2, MQ / 128), blk, 0, stream>>>(h1b, wt_f2, nullptr, xbuf, out, nullptr, 256, 0);

    // LN2 in-place on d_out
    ln_k<<<dim3(MQ), blk, 0, stream>>>(out, ln2_g, ln2_b, out, nullptr);
}

// Round 3
// 238.918 us; speedup vs baseline: 3.5740x; 1.2742x over previous
//
#include <hip/hip_runtime.h>
#include <cstdint>

#define EMBED 256
#define HEADS 8
#define LEVELS 4
#define POINTS 4
#define BS 2
#define NQ 16384
#define NV 21760          // 128*128+64*64+32*32+16*16
#define MQ (BS*NQ)        // 32768
#define MV (BS*NV)        // 43520

typedef __attribute__((ext_vector_type(8))) short short8;
typedef __attribute__((ext_vector_type(4))) float f32x4;

__device__ __forceinline__ unsigned short f2bf(float f) {
    unsigned int u = __float_as_uint(f);
    u = (u + 0x7FFFu + ((u >> 16) & 1u)) >> 16;   // RNE
    return (unsigned short)u;
}
__device__ __forceinline__ float bf2f(unsigned short h) {
    return __uint_as_float(((unsigned int)h) << 16);
}
__device__ __forceinline__ void glds16(const unsigned short* g, unsigned short* l) {
    __builtin_amdgcn_global_load_lds((const __attribute__((address_space(1))) void*)g,
                                     (__attribute__((address_space(3))) void*)l, 16, 0, 0);
}

// ---------------------------------------------------------------------------
// prep_wt: Wt[n][k] = bf16(W[k][n]) for 6 weight matrices (off+attn land in
// one concatenated [384][256] buffer). grid (384, 6).
// ---------------------------------------------------------------------------
struct WtArgs {
    const float* src[6];
    unsigned short* dst[6];
    int n[6];
};
__global__ __launch_bounds__(256) void prep_wt(WtArgs a)
{
    const int g = blockIdx.y;
    const int N = a.n[g];
    const int e = blockIdx.x * 256 + threadIdx.x;
    if (e >= 256 * N) return;
    const int k = e / N, n = e - k * N;
    a.dst[g][(size_t)n * 256 + k] = f2bf(a.src[g][e]);
}

// ---------------------------------------------------------------------------
// gemm_big: out(M x NCOLS) = A(M x 256) @ Wt^T + bias (+res) [LN] [relu]
// BM=128, BN=NCOLS (full width: 256 or 384), 512 threads = 8 waves (2m x 4n).
// A path: STAGEF32 ? reg-staged f32(+A2) with (seq,bs,C) row-remap + cvt
//                  : bf16 via global_load_lds(16B).
// B via global_load_lds. XOR k-slot swizzle (pre-swizzled source) both paths.
// LNF: full-row LayerNorm in epilogue (shfl_xor over frow + LDS over wn).
// ---------------------------------------------------------------------------
template<int NCOLS, int STAGEF32, int LNF, int RELUF>
__global__ __launch_bounds__(512) void gemm_big(
    const unsigned short* __restrict__ A,
    const float* __restrict__ Af, const float* __restrict__ A2f, int inner,
    const unsigned short* __restrict__ Bt,
    const float* __restrict__ bias0, const float* __restrict__ bias1,
    const float* __restrict__ res,
    const float* __restrict__ lng, const float* __restrict__ lnb,
    float* __restrict__ outf, unsigned short* __restrict__ outh)
{
    constexpr int FN = NCOLS / 64;                 // frags per wave in N
    __shared__ unsigned short As[128 * 32];
    __shared__ unsigned short Bs[NCOLS * 32];
    __shared__ float2 sdLN[LNF ? 128 : 1][4];

    const int t = threadIdx.x, l = t & 63, w = t >> 6;
    const int wm = w >> 2, wn = w & 3;
    const int frow = l & 15, fgrp = l >> 4;
    const size_t brow = (size_t)blockIdx.x * 128;

    const int fslot = fgrp ^ ((frow & 3) ^ ((frow >> 2) & 3));

    // gload staging map: lane l -> row seg*16+(l>>2), pre-swizzled src slot
    const int srow = l >> 2;
    const int sswz = (l & 3) ^ ((srow & 3) ^ ((srow >> 2) & 3));
    const unsigned short* gB0 = Bt + ((size_t)(w * 16 + srow)) * 256 + sswz * 8;

    const unsigned short* gA = nullptr;
    const float* srcA = nullptr; const float* srcA2 = nullptr;
    int arow_s = 0, aslot_s = 0, aswz_s = 0;
    if constexpr (STAGEF32) {
        arow_s = t >> 2; aslot_s = t & 3;
        const int grow = (int)brow + arow_s;
        const int bidx = grow / inner, nn = grow - bidx * inner;
        srcA = Af + (size_t)(nn * BS + bidx) * 256;
        if (A2f) srcA2 = A2f + (size_t)(nn * BS + bidx) * 256;
        aswz_s = aslot_s ^ ((arow_s & 3) ^ ((arow_s >> 2) & 3));
    } else {
        gA = A + (brow + (size_t)(w * 16 + srow)) * 256 + sswz * 8;
    }

    f32x4 acc[4][FN];
#pragma unroll
    for (int i = 0; i < 4; ++i)
#pragma unroll
        for (int j = 0; j < FN; ++j) acc[i][j] = f32x4{0.f, 0.f, 0.f, 0.f};

    float4 pA0, pA1, pC0, pC1;
    if constexpr (STAGEF32) {
        pA0 = *(const float4*)(srcA + aslot_s * 8);
        pA1 = *(const float4*)(srcA + aslot_s * 8 + 4);
        if (srcA2) { pC0 = *(const float4*)(srcA2 + aslot_s * 8);
                     pC1 = *(const float4*)(srcA2 + aslot_s * 8 + 4); }
    }

    for (int k0 = 0; k0 < 256; k0 += 32) {
        glds16(gB0 + k0,         (unsigned short*)&Bs[w * 512]);
        glds16(gB0 + 32768 + k0, (unsigned short*)&Bs[(w + 8) * 512]);
        if constexpr (NCOLS == 384)
            glds16(gB0 + 65536 + k0, (unsigned short*)&Bs[(w + 16) * 512]);

        if constexpr (STAGEF32) {
            float c[8] = {pA0.x, pA0.y, pA0.z, pA0.w, pA1.x, pA1.y, pA1.z, pA1.w};
            if (srcA2) {
                c[0] += pC0.x; c[1] += pC0.y; c[2] += pC0.z; c[3] += pC0.w;
                c[4] += pC1.x; c[5] += pC1.y; c[6] += pC1.z; c[7] += pC1.w;
            }
            short8 pk;
#pragma unroll
            for (int i = 0; i < 8; ++i) pk[i] = (short)f2bf(c[i]);
            *reinterpret_cast<short8*>(&As[arow_s * 32 + aswz_s * 8]) = pk;
            if (k0 + 32 < 256) {   // prefetch next k-tile early (hides under MFMA)
                pA0 = *(const float4*)(srcA + k0 + 32 + aslot_s * 8);
                pA1 = *(const float4*)(srcA + k0 + 32 + aslot_s * 8 + 4);
                if (srcA2) { pC0 = *(const float4*)(srcA2 + k0 + 32 + aslot_s * 8);
                             pC1 = *(const float4*)(srcA2 + k0 + 32 + aslot_s * 8 + 4); }
            }
        } else {
            glds16(gA + k0, (unsigned short*)&As[w * 512]);
        }
        __syncthreads();

        short8 af[4]; short8 bq[FN];
#pragma unroll
        for (int fm = 0; fm < 4; ++fm)
            af[fm] = *reinterpret_cast<const short8*>(&As[(wm * 64 + fm * 16 + frow) * 32 + fslot * 8]);
#pragma unroll
        for (int fn = 0; fn < FN; ++fn)
            bq[fn] = *reinterpret_cast<const short8*>(&Bs[(wn * (NCOLS / 4) + fn * 16 + frow) * 32 + fslot * 8]);
#pragma unroll
        for (int fm = 0; fm < 4; ++fm)
#pragma unroll
            for (int fn = 0; fn < FN; ++fn)
                acc[fm][fn] = __builtin_amdgcn_mfma_f32_16x16x32_bf16(af[fm], bq[fn], acc[fm][fn], 0, 0, 0);
        __syncthreads();
    }

    // ---- epilogue ----
    int cols[FN]; float bi[FN];
#pragma unroll
    for (int fn = 0; fn < FN; ++fn) {
        const int col = wn * (NCOLS / 4) + fn * 16 + frow;
        cols[fn] = col;
        float b = 0.f;
        if (bias0) {
            if (NCOLS == 384) b = (col < 256) ? bias0[col] : bias1[col - 256];
            else              b = bias0[col];
        }
        bi[fn] = b;
    }
#pragma unroll
    for (int fm = 0; fm < 4; ++fm)
#pragma unroll
        for (int j = 0; j < 4; ++j) {
            const size_t row = brow + wm * 64 + fm * 16 + fgrp * 4 + j;
#pragma unroll
            for (int fn = 0; fn < FN; ++fn) {
                float x = acc[fm][fn][j] + bi[fn];
                if (res)   x += res[row * NCOLS + cols[fn]];
                if (RELUF) x = fmaxf(x, 0.f);
                acc[fm][fn][j] = x;
            }
        }

    if constexpr (LNF) {
#pragma unroll
        for (int fm = 0; fm < 4; ++fm)
#pragma unroll
            for (int j = 0; j < 4; ++j) {
                float s1 = 0.f, s2 = 0.f;
#pragma unroll
                for (int fn = 0; fn < FN; ++fn) { const float x = acc[fm][fn][j]; s1 += x; s2 += x * x; }
#pragma unroll
                for (int o = 1; o < 16; o <<= 1) { s1 += __shfl_xor(s1, o); s2 += __shfl_xor(s2, o); }
                if (frow == 0)
                    sdLN[wm * 64 + fm * 16 + fgrp * 4 + j][wn] = make_float2(s1, s2);
            }
        __syncthreads();
        float gv[FN], bv[FN];
#pragma unroll
        for (int fn = 0; fn < FN; ++fn) { gv[fn] = lng[cols[fn]]; bv[fn] = lnb[cols[fn]]; }
#pragma unroll
        for (int fm = 0; fm < 4; ++fm)
#pragma unroll
            for (int j = 0; j < 4; ++j) {
                const int rl = wm * 64 + fm * 16 + fgrp * 4 + j;
                const float2 p0 = sdLN[rl][0], p1 = sdLN[rl][1], p2 = sdLN[rl][2], p3 = sdLN[rl][3];
                const float s1 = p0.x + p1.x + p2.x + p3.x;
                const float s2 = p0.y + p1.y + p2.y + p3.y;
                const float mu = s1 * (1.f / 256.f);
                const float var = s2 * (1.f / 256.f) - mu * mu;
                const float rstd = rsqrtf(var + 1e-5f);
                const size_t row = brow + rl;
#pragma unroll
                for (int fn = 0; fn < FN; ++fn) {
                    const float y = (acc[fm][fn][j] - mu) * rstd * gv[fn] + bv[fn];
                    if (outf) outf[row * NCOLS + cols[fn]] = y;
                    if (outh) outh[row * NCOLS + cols[fn]] = f2bf(y);
                }
            }
    } else {
#pragma unroll
        for (int fm = 0; fm < 4; ++fm)
#pragma unroll
            for (int j = 0; j < 4; ++j) {
                const size_t row = brow + wm * 64 + fm * 16 + fgrp * 4 + j;
#pragma unroll
                for (int fn = 0; fn < FN; ++fn) {
                    const float x = acc[fm][fn][j];
                    if (outf) outf[row * NCOLS + cols[fn]] = x;
                    if (outh) outh[row * NCOLS + cols[fn]] = f2bf(x);
                }
            }
    }
}

// ---------------------------------------------------------------------------
// Deformable sampler v3: 4 queries/block (256 thr). Descriptor phase computes
// per-(q,h,l,p,corner) weight+offset into padded LDS [4][8][65] (conflict-free
// stride-65: 8 distinct banks across heads, broadcast within 8 dq-lanes, imm
// ds_read offsets). Gather: thread=(q,h,dq) does 4 dims via 8B ushort4 loads.
// ---------------------------------------------------------------------------
__global__ __launch_bounds__(256) void sampler_k(
    const unsigned short* __restrict__ oa,    // [MQ][384]: off(256) | aw(128)
    const float* __restrict__ ref2d,          // [MQ][8]
    const unsigned short* __restrict__ v,     // [MV][256]
    unsigned short* __restrict__ outh)        // [MQ][256] nq-major
{
    const int q0 = blockIdx.x * 4;
    const int t = threadIdx.x;

    __shared__ float s_off[4][256];
    __shared__ float s_aw[4][128];
    __shared__ float s_ref[4][8];
    __shared__ uint2 s_d[4][8][65];

    {
        const int tq = t >> 6, c = (t & 63) * 4;
        const ushort4 u = *(const ushort4*)(oa + (size_t)(q0 + tq) * 384 + c);
        s_off[tq][c + 0] = bf2f(u.x); s_off[tq][c + 1] = bf2f(u.y);
        s_off[tq][c + 2] = bf2f(u.z); s_off[tq][c + 3] = bf2f(u.w);
    }
    if (t < 128) {
        const int tq = t >> 5, c = (t & 31) * 4;
        const ushort4 u = *(const ushort4*)(oa + (size_t)(q0 + tq) * 384 + 256 + c);
        s_aw[tq][c + 0] = bf2f(u.x); s_aw[tq][c + 1] = bf2f(u.y);
        s_aw[tq][c + 2] = bf2f(u.z); s_aw[tq][c + 3] = bf2f(u.w);
    }
    if (t < 32) {
        const int tq = t >> 3;
        s_ref[tq][t & 7] = ref2d[(size_t)(q0 + tq) * 8 + (t & 7)];
    }
    __syncthreads();

    if (t < 32) {                       // softmax per (query, head) over 16
        const int tq = t >> 3, h = t & 7;
        float* a = s_aw[tq] + h * 16;
        float m = -1e30f;
#pragma unroll
        for (int i = 0; i < 16; ++i) m = fmaxf(m, a[i]);
        float e[16], s = 0.f;
#pragma unroll
        for (int i = 0; i < 16; ++i) { e[i] = __expf(a[i] - m); s += e[i]; }
        const float inv = 1.f / s;
#pragma unroll
        for (int i = 0; i < 16; ++i) a[i] = e[i] * inv;
    }
    __syncthreads();

#pragma unroll
    for (int it = 0; it < 2; ++it) {    // 512 descriptors, 2 per thread
        const int item = t + it * 256;
        const int tq = item >> 7, hlp = item & 127;
        const int h = hlp >> 4, lp = hlp & 15, li = lp >> 2;
        const int Wl[4]  = {128, 64, 32, 16};
        const int S0l[4] = {0, 16384, 20480, 21504};
        const int Wi = Wl[li]; const float Wf = (float)Wi;
        const int b = (q0 + tq) >> 14;
        const float x = (s_ref[tq][li * 2 + 0] + s_off[tq][hlp * 2 + 0] / Wf) * Wf - 0.5f;
        const float y = (s_ref[tq][li * 2 + 1] + s_off[tq][hlp * 2 + 1] / Wf) * Wf - 0.5f;
        const float x0f = floorf(x), y0f = floorf(y);
        const float lx = x - x0f, ly = y - y0f;
        const int x0 = (int)x0f, y0 = (int)y0f;
        const float a = s_aw[tq][hlp];
        const float cw[4] = {(1.f - lx) * (1.f - ly) * a, lx * (1.f - ly) * a,
                             (1.f - lx) * ly * a,          lx * ly * a};
        const int base = b * NV + S0l[li];
#pragma unroll
        for (int c = 0; c < 4; ++c) {
            const int xi = x0 + (c & 1), yi = y0 + (c >> 1);
            const bool val = (xi >= 0) & (xi < Wi) & (yi >= 0) & (yi < Wi);
            const int xc = min(max(xi, 0), Wi - 1), yc = min(max(yi, 0), Wi - 1);
            const unsigned int ofs = (unsigned int)(base + yc * Wi + xc) * 256u + h * 32;
            s_d[tq][h][lp * 4 + c] = make_uint2(__float_as_uint(val ? cw[c] : 0.f), ofs);
        }
    }
    __syncthreads();

    const int tq = t >> 6, l = t & 63, h = l >> 3, dq = l & 7;
    const int rb = q0 + tq, b = rb >> 14, qi = rb & (NQ - 1);
    const unsigned short* vd = v + dq * 4;
    const uint2* dp = &s_d[tq][h][0];
    float a0 = 0.f, a1 = 0.f, a2 = 0.f, a3 = 0.f;
#pragma unroll
    for (int i = 0; i < 16; ++i) {
#pragma unroll
        for (int c = 0; c < 4; ++c) {
            const uint2 dd = dp[i * 4 + c];
            const uint2 raw = *(const uint2*)(vd + dd.y);
            const float wgt = __uint_as_float(dd.x);
            a0 += wgt * __uint_as_float(raw.x << 16);
            a1 += wgt * __uint_as_float(raw.x & 0xFFFF0000u);
            a2 += wgt * __uint_as_float(raw.y << 16);
            a3 += wgt * __uint_as_float(raw.y & 0xFFFF0000u);
        }
    }
    ushort4 o; o.x = f2bf(a0); o.y = f2bf(a1); o.z = f2bf(a2); o.w = f2bf(a3);
    *(ushort4*)(outh + (size_t)(qi * BS + b) * 256 + h * 32 + dq * 4) = o;
}

// ---------------------------------------------------------------------------
extern "C" void kernel_launch(void* const* d_in, const int* in_sizes, int n_in,
                              void* d_out, int out_size, void* d_ws, size_t ws_size,
                              hipStream_t stream)
{
    const float* lidar  = (const float*)d_in[0];
    const float* feat   = (const float*)d_in[1];
    const float* ref2d  = (const float*)d_in[2];
    const float* q_pose = (const float*)d_in[5];
    const float* W_off  = (const float*)d_in[6];
    const float* b_off  = (const float*)d_in[7];
    const float* W_attn = (const float*)d_in[8];
    const float* b_attn = (const float*)d_in[9];
    const float* W_val  = (const float*)d_in[10];
    const float* b_val  = (const float*)d_in[11];
    const float* W_out  = (const float*)d_in[12];
    const float* b_out  = (const float*)d_in[13];
    const float* ln1_g  = (const float*)d_in[14];
    const float* ln1_b  = (const float*)d_in[15];
    const float* ffn_w1 = (const float*)d_in[16];
    const float* ffn_w2 = (const float*)d_in[17];
    const float* ln2_g  = (const float*)d_in[18];
    const float* ln2_b  = (const float*)d_in[19];

    float* out = (float*)d_out;
    char*  ws  = (char*)d_ws;

    // byte offsets; high-water 98.5 MB
    unsigned short* vb   = (unsigned short*)(ws + 0);          // 22.28 MB
    unsigned short* oa   = (unsigned short*)(ws + 22282240);   // 25.17 MB
    unsigned short* smp  = (unsigned short*)(ws + 47448064);   // 16.78 MB
    float*          xbuf = (float*)(ws + 64225280);            // 33.55 MB
    unsigned short* xln  = (unsigned short*)(ws + 0);          // alias vb (dead)
    unsigned short* h1   = (unsigned short*)(ws + 47448064);   // alias smp (dead)
    unsigned short* wt   = (unsigned short*)(ws + 97779712);   // 0.72 MB
    unsigned short* wt_val = wt;
    unsigned short* wt_oa  = wt + 65536;          // [384][256]: off rows 0..255, attn 256..383
    unsigned short* wt_out = wt + 163840;
    unsigned short* wt_f1  = wt + 229376;
    unsigned short* wt_f2  = wt + 294912;

    WtArgs wa;
    wa.src[0] = W_val;  wa.dst[0] = wt_val;          wa.n[0] = 256;
    wa.src[1] = W_off;  wa.dst[1] = wt_oa;           wa.n[1] = 256;
    wa.src[2] = W_attn; wa.dst[2] = wt_oa + 65536;   wa.n[2] = 128;
    wa.src[3] = W_out;  wa.dst[3] = wt_out;          wa.n[3] = 256;
    wa.src[4] = ffn_w1; wa.dst[4] = wt_f1;           wa.n[4] = 256;
    wa.src[5] = ffn_w2; wa.dst[5] = wt_f2;           wa.n[5] = 256;
    prep_wt<<<dim3(384, 6), dim3(256), 0, stream>>>(wa);

    // value projection: feat f32 (remap inner=NV) -> vb bf16
    gemm_big<256, 1, 0, 0><<<dim3(MV / 128), dim3(512), 0, stream>>>(
        nullptr, feat, nullptr, NV, wt_val, b_val, nullptr,
        nullptr, nullptr, nullptr, nullptr, vb);

    // off+attn merged: (lidar+q_pose) f32 (remap inner=NQ) -> oa bf16 [MQ][384]
    gemm_big<384, 1, 0, 0><<<dim3(MQ / 128), dim3(512), 0, stream>>>(
        nullptr, lidar, q_pose, NQ, wt_oa, b_off, b_attn,
        nullptr, nullptr, nullptr, nullptr, oa);

    // deformable sampling (+softmax) -> smp bf16 nq-major
    sampler_k<<<dim3(MQ / 4), dim3(256), 0, stream>>>(oa, ref2d, vb, smp);

    // out-proj + bias + residual(lidar) + LN1 -> xbuf f32 + xln bf16
    gemm_big<256, 0, 1, 0><<<dim3(MQ / 128), dim3(512), 0, stream>>>(
        smp, nullptr, nullptr, 0, wt_out, b_out, nullptr,
        lidar, ln1_g, ln1_b, xbuf, xln);

    // FFN1: relu(x @ w1) -> h1 bf16
    gemm_big<256, 0, 0, 1><<<dim3(MQ / 128), dim3(512), 0, stream>>>(
        xln, nullptr, nullptr, 0, wt_f1, nullptr, nullptr,
        nullptr, nullptr, nullptr, nullptr, h1);

    // FFN2 + residual(xbuf) + LN2 -> d_out f32
    gemm_big<256, 0, 1, 0><<<dim3(MQ / 128), dim3(512), 0, stream>>>(
        h1, nullptr, nullptr, 0, wt_f2, nullptr, nullptr,
        xbuf, ln2_g, ln2_b, out, nullptr);
}

// Round 4
// 204.498 us; speedup vs baseline: 4.1756x; 1.1683x over previous
//
#include <hip/hip_runtime.h>
#include <cstdint>

#define EMBED 256
#define HEADS 8
#define LEVELS 4
#define POINTS 4
#define BS 2
#define NQ 16384
#define NV 21760          // 128*128+64*64+32*32+16*16
#define MQ (BS*NQ)        // 32768
#define MV (BS*NV)        // 43520

typedef __attribute__((ext_vector_type(8))) short short8;
typedef __attribute__((ext_vector_type(4))) float f32x4;

__device__ __forceinline__ unsigned short f2bf(float f) {
    unsigned int u = __float_as_uint(f);
    u = (u + 0x7FFFu + ((u >> 16) & 1u)) >> 16;   // RNE
    return (unsigned short)u;
}
__device__ __forceinline__ float bf2f(unsigned short h) {
    return __uint_as_float(((unsigned int)h) << 16);
}
__device__ __forceinline__ void glds16(const unsigned short* g, unsigned short* l) {
    __builtin_amdgcn_global_load_lds((const __attribute__((address_space(1))) void*)g,
                                     (__attribute__((address_space(3))) void*)l, 16, 0, 0);
}

// ---------------------------------------------------------------------------
// prep_wt: Wt[n][k] = bf16(W[k][n]) for 6 weight matrices (off+attn share one
// concatenated [384][256] buffer). grid (384, 6).
// ---------------------------------------------------------------------------
struct WtArgs {
    const float* src[6];
    unsigned short* dst[6];
    int n[6];
};
__global__ __launch_bounds__(256) void prep_wt(WtArgs a)
{
    const int g = blockIdx.y;
    const int N = a.n[g];
    const int e = blockIdx.x * 256 + threadIdx.x;
    if (e >= 256 * N) return;
    const int k = e / N, n = e - k * N;
    a.dst[g][(size_t)n * 256 + k] = f2bf(a.src[g][e]);
}

// ---------------------------------------------------------------------------
// gemm_big: out(M x NCOLS) = A(M x 256) @ Wt^T + bias (+res) [LN] [relu]
// (unchanged structure from R3; out-proj now writes only bf16)
// ---------------------------------------------------------------------------
template<int NCOLS, int STAGEF32, int LNF, int RELUF>
__global__ __launch_bounds__(512) void gemm_big(
    const unsigned short* __restrict__ A,
    const float* __restrict__ Af, const float* __restrict__ A2f, int inner,
    const unsigned short* __restrict__ Bt,
    const float* __restrict__ bias0, const float* __restrict__ bias1,
    const float* __restrict__ res,
    const float* __restrict__ lng, const float* __restrict__ lnb,
    float* __restrict__ outf, unsigned short* __restrict__ outh)
{
    constexpr int FN = NCOLS / 64;
    __shared__ unsigned short As[128 * 32];
    __shared__ unsigned short Bs[NCOLS * 32];
    __shared__ float2 sdLN[LNF ? 128 : 1][4];

    const int t = threadIdx.x, l = t & 63, w = t >> 6;
    const int wm = w >> 2, wn = w & 3;
    const int frow = l & 15, fgrp = l >> 4;
    const size_t brow = (size_t)blockIdx.x * 128;

    const int fslot = fgrp ^ ((frow & 3) ^ ((frow >> 2) & 3));
    const int srow = l >> 2;
    const int sswz = (l & 3) ^ ((srow & 3) ^ ((srow >> 2) & 3));
    const unsigned short* gB0 = Bt + ((size_t)(w * 16 + srow)) * 256 + sswz * 8;

    const unsigned short* gA = nullptr;
    const float* srcA = nullptr; const float* srcA2 = nullptr;
    int arow_s = 0, aslot_s = 0, aswz_s = 0;
    if constexpr (STAGEF32) {
        arow_s = t >> 2; aslot_s = t & 3;
        const int grow = (int)brow + arow_s;
        const int bidx = grow / inner, nn = grow - bidx * inner;
        srcA = Af + (size_t)(nn * BS + bidx) * 256;
        if (A2f) srcA2 = A2f + (size_t)(nn * BS + bidx) * 256;
        aswz_s = aslot_s ^ ((arow_s & 3) ^ ((arow_s >> 2) & 3));
    } else {
        gA = A + (brow + (size_t)(w * 16 + srow)) * 256 + sswz * 8;
    }

    f32x4 acc[4][FN];
#pragma unroll
    for (int i = 0; i < 4; ++i)
#pragma unroll
        for (int j = 0; j < FN; ++j) acc[i][j] = f32x4{0.f, 0.f, 0.f, 0.f};

    float4 pA0, pA1, pC0, pC1;
    if constexpr (STAGEF32) {
        pA0 = *(const float4*)(srcA + aslot_s * 8);
        pA1 = *(const float4*)(srcA + aslot_s * 8 + 4);
        if (srcA2) { pC0 = *(const float4*)(srcA2 + aslot_s * 8);
                     pC1 = *(const float4*)(srcA2 + aslot_s * 8 + 4); }
    }

    for (int k0 = 0; k0 < 256; k0 += 32) {
        glds16(gB0 + k0,         (unsigned short*)&Bs[w * 512]);
        glds16(gB0 + 32768 + k0, (unsigned short*)&Bs[(w + 8) * 512]);
        if constexpr (NCOLS == 384)
            glds16(gB0 + 65536 + k0, (unsigned short*)&Bs[(w + 16) * 512]);

        if constexpr (STAGEF32) {
            float c[8] = {pA0.x, pA0.y, pA0.z, pA0.w, pA1.x, pA1.y, pA1.z, pA1.w};
            if (srcA2) {
                c[0] += pC0.x; c[1] += pC0.y; c[2] += pC0.z; c[3] += pC0.w;
                c[4] += pC1.x; c[5] += pC1.y; c[6] += pC1.z; c[7] += pC1.w;
            }
            short8 pk;
#pragma unroll
            for (int i = 0; i < 8; ++i) pk[i] = (short)f2bf(c[i]);
            *reinterpret_cast<short8*>(&As[arow_s * 32 + aswz_s * 8]) = pk;
            if (k0 + 32 < 256) {
                pA0 = *(const float4*)(srcA + k0 + 32 + aslot_s * 8);
                pA1 = *(const float4*)(srcA + k0 + 32 + aslot_s * 8 + 4);
                if (srcA2) { pC0 = *(const float4*)(srcA2 + k0 + 32 + aslot_s * 8);
                             pC1 = *(const float4*)(srcA2 + k0 + 32 + aslot_s * 8 + 4); }
            }
        } else {
            glds16(gA + k0, (unsigned short*)&As[w * 512]);
        }
        __syncthreads();

        short8 af[4]; short8 bq[FN];
#pragma unroll
        for (int fm = 0; fm < 4; ++fm)
            af[fm] = *reinterpret_cast<const short8*>(&As[(wm * 64 + fm * 16 + frow) * 32 + fslot * 8]);
#pragma unroll
        for (int fn = 0; fn < FN; ++fn)
            bq[fn] = *reinterpret_cast<const short8*>(&Bs[(wn * (NCOLS / 4) + fn * 16 + frow) * 32 + fslot * 8]);
#pragma unroll
        for (int fm = 0; fm < 4; ++fm)
#pragma unroll
            for (int fn = 0; fn < FN; ++fn)
                acc[fm][fn] = __builtin_amdgcn_mfma_f32_16x16x32_bf16(af[fm], bq[fn], acc[fm][fn], 0, 0, 0);
        __syncthreads();
    }

    int cols[FN]; float bi[FN];
#pragma unroll
    for (int fn = 0; fn < FN; ++fn) {
        const int col = wn * (NCOLS / 4) + fn * 16 + frow;
        cols[fn] = col;
        float b = 0.f;
        if (bias0) {
            if (NCOLS == 384) b = (col < 256) ? bias0[col] : bias1[col - 256];
            else              b = bias0[col];
        }
        bi[fn] = b;
    }
#pragma unroll
    for (int fm = 0; fm < 4; ++fm)
#pragma unroll
        for (int j = 0; j < 4; ++j) {
            const size_t row = brow + wm * 64 + fm * 16 + fgrp * 4 + j;
#pragma unroll
            for (int fn = 0; fn < FN; ++fn) {
                float x = acc[fm][fn][j] + bi[fn];
                if (res)   x += res[row * NCOLS + cols[fn]];
                if (RELUF) x = fmaxf(x, 0.f);
                acc[fm][fn][j] = x;
            }
        }

    if constexpr (LNF) {
#pragma unroll
        for (int fm = 0; fm < 4; ++fm)
#pragma unroll
            for (int j = 0; j < 4; ++j) {
                float s1 = 0.f, s2 = 0.f;
#pragma unroll
                for (int fn = 0; fn < FN; ++fn) { const float x = acc[fm][fn][j]; s1 += x; s2 += x * x; }
#pragma unroll
                for (int o = 1; o < 16; o <<= 1) { s1 += __shfl_xor(s1, o); s2 += __shfl_xor(s2, o); }
                if (frow == 0)
                    sdLN[wm * 64 + fm * 16 + fgrp * 4 + j][wn] = make_float2(s1, s2);
            }
        __syncthreads();
        float gv[FN], bv[FN];
#pragma unroll
        for (int fn = 0; fn < FN; ++fn) { gv[fn] = lng[cols[fn]]; bv[fn] = lnb[cols[fn]]; }
#pragma unroll
        for (int fm = 0; fm < 4; ++fm)
#pragma unroll
            for (int j = 0; j < 4; ++j) {
                const int rl = wm * 64 + fm * 16 + fgrp * 4 + j;
                const float2 p0 = sdLN[rl][0], p1 = sdLN[rl][1], p2 = sdLN[rl][2], p3 = sdLN[rl][3];
                const float s1 = p0.x + p1.x + p2.x + p3.x;
                const float s2 = p0.y + p1.y + p2.y + p3.y;
                const float mu = s1 * (1.f / 256.f);
                const float var = s2 * (1.f / 256.f) - mu * mu;
                const float rstd = rsqrtf(var + 1e-5f);
                const size_t row = brow + rl;
#pragma unroll
                for (int fn = 0; fn < FN; ++fn) {
                    const float y = (acc[fm][fn][j] - mu) * rstd * gv[fn] + bv[fn];
                    if (outf) outf[row * NCOLS + cols[fn]] = y;
                    if (outh) outh[row * NCOLS + cols[fn]] = f2bf(y);
                }
            }
    } else {
#pragma unroll
        for (int fm = 0; fm < 4; ++fm)
#pragma unroll
            for (int j = 0; j < 4; ++j) {
                const size_t row = brow + wm * 64 + fm * 16 + fgrp * 4 + j;
#pragma unroll
                for (int fn = 0; fn < FN; ++fn) {
                    const float x = acc[fm][fn][j];
                    if (outf) outf[row * NCOLS + cols[fn]] = x;
                    if (outh) outh[row * NCOLS + cols[fn]] = f2bf(x);
                }
            }
    }
}

// ---------------------------------------------------------------------------
// ffn_fused: per 64-row block — h = relu(X@W1); out = LN2(h@W2 + X).
// X bf16 [MQ][256]; W1t/W2t bf16 [256][256] k-major. h lives in swizzled LDS.
// 512 threads = 8 waves (2m x 4n); acc[2][4]. Residual re-read from X (bf16).
// ---------------------------------------------------------------------------
__global__ __launch_bounds__(512) void ffn_fused(
    const unsigned short* __restrict__ X,
    const unsigned short* __restrict__ W1t, const unsigned short* __restrict__ W2t,
    const float* __restrict__ lng, const float* __restrict__ lnb,
    float* __restrict__ outf)
{
    __shared__ unsigned short As[64 * 32];     // 4 KB X stage
    __shared__ unsigned short Bs[256 * 32];    // 16 KB W stage
    __shared__ unsigned short Hs[64 * 256];    // 32 KB h tile (slot-swizzled)
    __shared__ float2 sdLN[64][4];

    const int t = threadIdx.x, l = t & 63, w = t >> 6;
    const int wm = w >> 2, wn = w & 3;
    const int frow = l & 15, fgrp = l >> 4;
    const size_t brow = (size_t)blockIdx.x * 64;

    const int fslot = fgrp ^ ((frow & 3) ^ ((frow >> 2) & 3));
    const int srow = l >> 2;
    const int sswz = (l & 3) ^ ((srow & 3) ^ ((srow >> 2) & 3));

    const unsigned short* gX  = X + (brow + (size_t)((w & 3) * 16 + srow)) * 256 + sswz * 8;
    const unsigned short* gW1 = W1t + ((size_t)(w * 16 + srow)) * 256 + sswz * 8;
    const unsigned short* gW2 = W2t + ((size_t)(w * 16 + srow)) * 256 + sswz * 8;

    f32x4 acc[2][4];

    // ---------------- GEMM1: h = relu(X @ W1) ----------------
#pragma unroll
    for (int i = 0; i < 2; ++i)
#pragma unroll
        for (int j = 0; j < 4; ++j) acc[i][j] = f32x4{0.f, 0.f, 0.f, 0.f};

    for (int k0 = 0; k0 < 256; k0 += 32) {
        glds16(gW1 + k0,         (unsigned short*)&Bs[w * 512]);
        glds16(gW1 + 32768 + k0, (unsigned short*)&Bs[(w + 8) * 512]);
        if (w < 4) glds16(gX + k0, (unsigned short*)&As[w * 512]);
        __syncthreads();

        short8 af[2], bq[4];
#pragma unroll
        for (int fm = 0; fm < 2; ++fm)
            af[fm] = *reinterpret_cast<const short8*>(&As[(wm * 32 + fm * 16 + frow) * 32 + fslot * 8]);
#pragma unroll
        for (int fn = 0; fn < 4; ++fn)
            bq[fn] = *reinterpret_cast<const short8*>(&Bs[(wn * 64 + fn * 16 + frow) * 32 + fslot * 8]);
#pragma unroll
        for (int fm = 0; fm < 2; ++fm)
#pragma unroll
            for (int fn = 0; fn < 4; ++fn)
                acc[fm][fn] = __builtin_amdgcn_mfma_f32_16x16x32_bf16(af[fm], bq[fn], acc[fm][fn], 0, 0, 0);
        __syncthreads();
    }

    // epilogue1: relu -> Hs (slot-swizzled: slot' = (col>>3) ^ (row&7))
#pragma unroll
    for (int fm = 0; fm < 2; ++fm)
#pragma unroll
        for (int fn = 0; fn < 4; ++fn) {
            const int col = wn * 64 + fn * 16 + frow;
#pragma unroll
            for (int j = 0; j < 4; ++j) {
                const int row = wm * 32 + fm * 16 + fgrp * 4 + j;
                const int ss = (col >> 3) ^ (row & 7);
                Hs[row * 256 + ss * 8 + (col & 7)] = f2bf(fmaxf(acc[fm][fn][j], 0.f));
            }
        }
    __syncthreads();

    // ---------------- GEMM2: out = h @ W2 + X; LN2 ----------------
#pragma unroll
    for (int i = 0; i < 2; ++i)
#pragma unroll
        for (int j = 0; j < 4; ++j) acc[i][j] = f32x4{0.f, 0.f, 0.f, 0.f};

    for (int k0 = 0; k0 < 256; k0 += 32) {
        glds16(gW2 + k0,         (unsigned short*)&Bs[w * 512]);
        glds16(gW2 + 32768 + k0, (unsigned short*)&Bs[(w + 8) * 512]);
        __syncthreads();

        short8 af[2], bq[4];
#pragma unroll
        for (int fm = 0; fm < 2; ++fm) {
            const int row = wm * 32 + fm * 16 + frow;
            const int ksg = (k0 >> 3) + fgrp;                  // global 8-elem k-slot
            const int ss = ksg ^ (row & 7);
            af[fm] = *reinterpret_cast<const short8*>(&Hs[row * 256 + ss * 8]);
        }
#pragma unroll
        for (int fn = 0; fn < 4; ++fn)
            bq[fn] = *reinterpret_cast<const short8*>(&Bs[(wn * 64 + fn * 16 + frow) * 32 + fslot * 8]);
#pragma unroll
        for (int fm = 0; fm < 2; ++fm)
#pragma unroll
            for (int fn = 0; fn < 4; ++fn)
                acc[fm][fn] = __builtin_amdgcn_mfma_f32_16x16x32_bf16(af[fm], bq[fn], acc[fm][fn], 0, 0, 0);
        __syncthreads();
    }

    // epilogue2: + residual X, LN2, write f32
#pragma unroll
    for (int fm = 0; fm < 2; ++fm)
#pragma unroll
        for (int fn = 0; fn < 4; ++fn) {
            const int col = wn * 64 + fn * 16 + frow;
#pragma unroll
            for (int j = 0; j < 4; ++j) {
                const size_t row = brow + wm * 32 + fm * 16 + fgrp * 4 + j;
                acc[fm][fn][j] += bf2f(X[row * 256 + col]);
            }
        }
#pragma unroll
    for (int fm = 0; fm < 2; ++fm)
#pragma unroll
        for (int j = 0; j < 4; ++j) {
            float s1 = 0.f, s2 = 0.f;
#pragma unroll
            for (int fn = 0; fn < 4; ++fn) { const float x = acc[fm][fn][j]; s1 += x; s2 += x * x; }
#pragma unroll
            for (int o = 1; o < 16; o <<= 1) { s1 += __shfl_xor(s1, o); s2 += __shfl_xor(s2, o); }
            if (frow == 0)
                sdLN[wm * 32 + fm * 16 + fgrp * 4 + j][wn] = make_float2(s1, s2);
        }
    __syncthreads();
#pragma unroll
    for (int fm = 0; fm < 2; ++fm)
#pragma unroll
        for (int j = 0; j < 4; ++j) {
            const int rl = wm * 32 + fm * 16 + fgrp * 4 + j;
            const float2 p0 = sdLN[rl][0], p1 = sdLN[rl][1], p2 = sdLN[rl][2], p3 = sdLN[rl][3];
            const float s1 = p0.x + p1.x + p2.x + p3.x;
            const float s2 = p0.y + p1.y + p2.y + p3.y;
            const float mu = s1 * (1.f / 256.f);
            const float var = s2 * (1.f / 256.f) - mu * mu;
            const float rstd = rsqrtf(var + 1e-5f);
            const size_t row = brow + rl;
#pragma unroll
            for (int fn = 0; fn < 4; ++fn) {
                const int col = wn * 64 + fn * 16 + frow;
                outf[row * 256 + col] = (acc[fm][fn][j] - mu) * rstd * lng[col] + lnb[col];
            }
        }
}

// ---------------------------------------------------------------------------
// Deformable sampler v4: 4 queries/block, descriptor LDS as R3, gather phase
// register-pipelined two-deep (16 descriptors -> 16 8B loads in flight while
// previous 16 FMA). thread = (tq, h, dq): 4 dims via 8B loads.
// ---------------------------------------------------------------------------
#define LDDESC(dst, base)                         \
    _Pragma("unroll")                             \
    for (int j = 0; j < 16; ++j) dst[j] = dp[(base) + j];
#define LDRAW(dst, dsc)                           \
    _Pragma("unroll")                             \
    for (int j = 0; j < 16; ++j) dst[j] = *(const uint2*)(vd + dsc[j].y);
#define FMA16(dsc, raw)                           \
    _Pragma("unroll")                             \
    for (int j = 0; j < 16; ++j) {                \
        const float wgt = __uint_as_float(dsc[j].x);            \
        a0 += wgt * __uint_as_float(raw[j].x << 16);            \
        a1 += wgt * __uint_as_float(raw[j].x & 0xFFFF0000u);    \
        a2 += wgt * __uint_as_float(raw[j].y << 16);            \
        a3 += wgt * __uint_as_float(raw[j].y & 0xFFFF0000u);    \
    }

__global__ __launch_bounds__(256) void sampler_k(
    const unsigned short* __restrict__ oa,    // [MQ][384]: off(256) | aw(128)
    const float* __restrict__ ref2d,          // [MQ][8]
    const unsigned short* __restrict__ v,     // [MV][256]
    unsigned short* __restrict__ outh)        // [MQ][256] nq-major
{
    const int q0 = blockIdx.x * 4;
    const int t = threadIdx.x;

    __shared__ float s_off[4][256];
    __shared__ float s_aw[4][128];
    __shared__ float s_ref[4][8];
    __shared__ uint2 s_d[4][8][65];

    {
        const int tq = t >> 6, c = (t & 63) * 4;
        const ushort4 u = *(const ushort4*)(oa + (size_t)(q0 + tq) * 384 + c);
        s_off[tq][c + 0] = bf2f(u.x); s_off[tq][c + 1] = bf2f(u.y);
        s_off[tq][c + 2] = bf2f(u.z); s_off[tq][c + 3] = bf2f(u.w);
    }
    if (t < 128) {
        const int tq = t >> 5, c = (t & 31) * 4;
        const ushort4 u = *(const ushort4*)(oa + (size_t)(q0 + tq) * 384 + 256 + c);
        s_aw[tq][c + 0] = bf2f(u.x); s_aw[tq][c + 1] = bf2f(u.y);
        s_aw[tq][c + 2] = bf2f(u.z); s_aw[tq][c + 3] = bf2f(u.w);
    }
    if (t < 32) {
        const int tq = t >> 3;
        s_ref[tq][t & 7] = ref2d[(size_t)(q0 + tq) * 8 + (t & 7)];
    }
    __syncthreads();

    if (t < 32) {                       // softmax per (query, head) over 16
        const int tq = t >> 3, h = t & 7;
        float* a = s_aw[tq] + h * 16;
        float m = -1e30f;
#pragma unroll
        for (int i = 0; i < 16; ++i) m = fmaxf(m, a[i]);
        float e[16], s = 0.f;
#pragma unroll
        for (int i = 0; i < 16; ++i) { e[i] = __expf(a[i] - m); s += e[i]; }
        const float inv = 1.f / s;
#pragma unroll
        for (int i = 0; i < 16; ++i) a[i] = e[i] * inv;
    }
    __syncthreads();

#pragma unroll
    for (int it = 0; it < 2; ++it) {    // 512 descriptors, 2 per thread
        const int item = t + it * 256;
        const int tq = item >> 7, hlp = item & 127;
        const int h = hlp >> 4, lp = hlp & 15, li = lp >> 2;
        const int Wl[4]  = {128, 64, 32, 16};
        const int S0l[4] = {0, 16384, 20480, 21504};
        const int Wi = Wl[li]; const float Wf = (float)Wi;
        const int b = (q0 + tq) >> 14;
        const float x = (s_ref[tq][li * 2 + 0] + s_off[tq][hlp * 2 + 0] / Wf) * Wf - 0.5f;
        const float y = (s_ref[tq][li * 2 + 1] + s_off[tq][hlp * 2 + 1] / Wf) * Wf - 0.5f;
        const float x0f = floorf(x), y0f = floorf(y);
        const float lx = x - x0f, ly = y - y0f;
        const int x0 = (int)x0f, y0 = (int)y0f;
        const float a = s_aw[tq][hlp];
        const float cw[4] = {(1.f - lx) * (1.f - ly) * a, lx * (1.f - ly) * a,
                             (1.f - lx) * ly * a,          lx * ly * a};
        const int base = b * NV + S0l[li];
#pragma unroll
        for (int c = 0; c < 4; ++c) {
            const int xi = x0 + (c & 1), yi = y0 + (c >> 1);
            const bool val = (xi >= 0) & (xi < Wi) & (yi >= 0) & (yi < Wi);
            const int xc = min(max(xi, 0), Wi - 1), yc = min(max(yi, 0), Wi - 1);
            const unsigned int ofs = (unsigned int)(base + yc * Wi + xc) * 256u + h * 32;
            s_d[tq][h][lp * 4 + c] = make_uint2(__float_as_uint(val ? cw[c] : 0.f), ofs);
        }
    }
    __syncthreads();

    const int tq = t >> 6, l = t & 63, h = l >> 3, dq = l & 7;
    const int rb = q0 + tq, b = rb >> 14, qi = rb & (NQ - 1);
    const unsigned short* vd = v + dq * 4;
    const uint2* dp = &s_d[tq][h][0];
    float a0 = 0.f, a1 = 0.f, a2 = 0.f, a3 = 0.f;

    uint2 dA[16], dB[16], rA[16], rB[16];
    LDDESC(dA, 0)
    LDRAW(rA, dA)
    LDDESC(dB, 16)
    LDRAW(rB, dB)
    FMA16(dA, rA)
    LDDESC(dA, 32)
    LDRAW(rA, dA)
    FMA16(dB, rB)
    LDDESC(dB, 48)
    LDRAW(rB, dB)
    FMA16(dA, rA)
    FMA16(dB, rB)

    ushort4 o; o.x = f2bf(a0); o.y = f2bf(a1); o.z = f2bf(a2); o.w = f2bf(a3);
    *(ushort4*)(outh + (size_t)(qi * BS + b) * 256 + h * 32 + dq * 4) = o;
}

// ---------------------------------------------------------------------------
extern "C" void kernel_launch(void* const* d_in, const int* in_sizes, int n_in,
                              void* d_out, int out_size, void* d_ws, size_t ws_size,
                              hipStream_t stream)
{
    const float* lidar  = (const float*)d_in[0];
    const float* feat   = (const float*)d_in[1];
    const float* ref2d  = (const float*)d_in[2];
    const float* q_pose = (const float*)d_in[5];
    const float* W_off  = (const float*)d_in[6];
    const float* b_off  = (const float*)d_in[7];
    const float* W_attn = (const float*)d_in[8];
    const float* b_attn = (const float*)d_in[9];
    const float* W_val  = (const float*)d_in[10];
    const float* b_val  = (const float*)d_in[11];
    const float* W_out  = (const float*)d_in[12];
    const float* b_out  = (const float*)d_in[13];
    const float* ln1_g  = (const float*)d_in[14];
    const float* ln1_b  = (const float*)d_in[15];
    const float* ffn_w1 = (const float*)d_in[16];
    const float* ffn_w2 = (const float*)d_in[17];
    const float* ln2_g  = (const float*)d_in[18];
    const float* ln2_b  = (const float*)d_in[19];

    float* out = (float*)d_out;
    char*  ws  = (char*)d_ws;

    // byte offsets; high-water ~81.7 MB
    unsigned short* vb   = (unsigned short*)(ws + 0);          // 22.28 MB
    unsigned short* oa   = (unsigned short*)(ws + 22282240);   // 25.17 MB
    unsigned short* smp  = (unsigned short*)(ws + 47448064);   // 16.78 MB
    unsigned short* xln  = (unsigned short*)(ws + 64225280);   // 16.78 MB
    unsigned short* wt   = (unsigned short*)(ws + 81002496);   // 0.72 MB
    unsigned short* wt_val = wt;
    unsigned short* wt_oa  = wt + 65536;          // [384][256]
    unsigned short* wt_out = wt + 163840;
    unsigned short* wt_f1  = wt + 229376;
    unsigned short* wt_f2  = wt + 294912;

    WtArgs wa;
    wa.src[0] = W_val;  wa.dst[0] = wt_val;          wa.n[0] = 256;
    wa.src[1] = W_off;  wa.dst[1] = wt_oa;           wa.n[1] = 256;
    wa.src[2] = W_attn; wa.dst[2] = wt_oa + 65536;   wa.n[2] = 128;
    wa.src[3] = W_out;  wa.dst[3] = wt_out;          wa.n[3] = 256;
    wa.src[4] = ffn_w1; wa.dst[4] = wt_f1;           wa.n[4] = 256;
    wa.src[5] = ffn_w2; wa.dst[5] = wt_f2;           wa.n[5] = 256;
    prep_wt<<<dim3(384, 6), dim3(256), 0, stream>>>(wa);

    // value projection: feat f32 (remap inner=NV) -> vb bf16
    gemm_big<256, 1, 0, 0><<<dim3(MV / 128), dim3(512), 0, stream>>>(
        nullptr, feat, nullptr, NV, wt_val, b_val, nullptr,
        nullptr, nullptr, nullptr, nullptr, vb);

    // off+attn merged: (lidar+q_pose) f32 -> oa bf16 [MQ][384]
    gemm_big<384, 1, 0, 0><<<dim3(MQ / 128), dim3(512), 0, stream>>>(
        nullptr, lidar, q_pose, NQ, wt_oa, b_off, b_attn,
        nullptr, nullptr, nullptr, nullptr, oa);

    // deformable sampling (+softmax) -> smp bf16 nq-major
    sampler_k<<<dim3(MQ / 4), dim3(256), 0, stream>>>(oa, ref2d, vb, smp);

    // out-proj + bias + residual(lidar f32) + LN1 -> xln bf16 only
    gemm_big<256, 0, 1, 0><<<dim3(MQ / 128), dim3(512), 0, stream>>>(
        smp, nullptr, nullptr, 0, wt_out, b_out, nullptr,
        lidar, ln1_g, ln1_b, nullptr, xln);

    // fused FFN1+FFN2+LN2 -> d_out f32
    ffn_fused<<<dim3(MQ / 64), dim3(512), 0, stream>>>(
        xln, wt_f1, wt_f2, ln2_g, ln2_b, out);
}